// Round 11
// baseline (316.830 us; speedup 1.0000x reference)
//
// CAM+SE module, MI355X gfx950.
// R11: R10 with the compile fix — LDS buffer selection via scalar pointers
// + ternary (brace-initialized pointer ARRAYS from __shared__ emit an
// addrspacecast static initializer that gfx950 rejects). No other changes.
#include <hip/hip_runtime.h>
#include <cstdint>
#include <cstddef>

#define B_ 16
#define C_ 512
#define N_ 4096   // H*W
#define CH_ 64    // C/8

#define VMWAIT(n) asm volatile("s_waitcnt vmcnt(" #n ")" ::: "memory")
#define LGKM0()   asm volatile("s_waitcnt lgkmcnt(0)" ::: "memory")
#define BARRAW()  asm volatile("s_barrier" ::: "memory")

typedef __attribute__((ext_vector_type(8))) short short8;
typedef __attribute__((ext_vector_type(4))) short short4t;
typedef __attribute__((ext_vector_type(4))) float f32x4;

__device__ __forceinline__ unsigned short f2bf(float f) {
  union { float f; unsigned u; } v; v.f = f;
  unsigned r = v.u + 0x7FFFu + ((v.u >> 16) & 1u);   // RNE
  return (unsigned short)(r >> 16);
}
__device__ __forceinline__ float bf2f(unsigned short u) {
  union { unsigned u; float f; } v; v.u = ((unsigned)u) << 16;
  return v.f;
}
__device__ __forceinline__ ushort4 cvt4(float4 v) {
  ushort4 u; u.x = f2bf(v.x); u.y = f2bf(v.y); u.z = f2bf(v.z); u.w = f2bf(v.w);
  return u;
}
__device__ __forceinline__ void gload_lds16(const void* g, void* l) {
  __builtin_amdgcn_global_load_lds((__attribute__((address_space(1))) void*)g,
                                   (__attribute__((address_space(3))) void*)l,
                                   16, 0, 0);
}
__device__ __forceinline__ unsigned lds_off(const void* p) {
  return (unsigned)(size_t)(__attribute__((address_space(3))) const char*)p;
}

// ================= k3 helpers (unchanged from R9) =================
template <int CPW>
__device__ __forceinline__ void stage_pair(
    const unsigned short* __restrict__ Asrc, const unsigned short* __restrict__ Bsrc,
    char* Adst, char* Bdst, int t, int ko, bool doB) {
  const int l = t & 63, wid = t >> 6;
  const int srow = l >> 3, scc = l & 7;
#pragma unroll
  for (int i = 0; i < CPW; ++i) {
    const int chunk = wid * CPW + i;
    const int row = chunk * 8 + srow;
    const int cc = scc ^ (row & 7);
    gload_lds16(Asrc + (size_t)row * N_ + ko + cc * 8, Adst + chunk * 1024);
    if (doB)
      gload_lds16(Bsrc + (size_t)row * N_ + ko + cc * 8, Bdst + chunk * 1024);
  }
}
template <int MF, int NF>
__device__ __forceinline__ void gemm_step_t(const char* Abase, const char* Bbase,
                                            int l, int wA, int wB,
                                            f32x4 (&acc)[MF][NF]) {
#pragma unroll
  for (int ks = 0; ks < 2; ++ks) {
    short8 af[MF], bfv[NF];
#pragma unroll
    for (int m = 0; m < MF; ++m) {
      const int row = wA * (MF * 16) + m * 16 + (l & 15);
      const int ch = (ks * 4 + (l >> 4)) ^ (row & 7);
      af[m] = *(const short8*)(Abase + row * 128 + ch * 16);
    }
#pragma unroll
    for (int n = 0; n < NF; ++n) {
      const int row = wB * (NF * 16) + n * 16 + (l & 15);
      const int ch = (ks * 4 + (l >> 4)) ^ (row & 7);
      bfv[n] = *(const short8*)(Bbase + row * 128 + ch * 16);
    }
#pragma unroll
    for (int m = 0; m < MF; ++m)
#pragma unroll
      for (int n = 0; n < NF; ++n)
        acc[m][n] = __builtin_amdgcn_mfma_f32_16x16x32_bf16(af[m], bfv[n],
                                                            acc[m][n], 0, 0, 0);
  }
}

// ================= k5 staging (256^2 tile) =================
// att: 256 c-rows x 64 d, row-major 128B rows, XOR-swizzled source (rule 21).
__device__ __forceinline__ void stage_att256(
    const unsigned short* __restrict__ src, char* dst, int t, int ko) {
  const int l = t & 63, wid = t >> 6;
  const int srow = l >> 3, scc = l & 7;
#pragma unroll
  for (int i = 0; i < 4; ++i) {
    const int chunk = wid * 4 + i;
    const int row = chunk * 8 + srow;
    const int cc = scc ^ (row & 7);
    gload_lds16(src + (size_t)row * C_ + ko + cc * 8, dst + chunk * 1024);
  }
}
// q: 64 d x 256 n from qbf (d-major) into tr-subtiled LDS:
// (d,n) at (d>>2)*2048 + (n>>4)*128 + (d&3)*32 + (n&15)*2.
// dest chunk*1024 + l*16 <=> src d=(chunk>>1)*4+((l>>1)&3),
// n=(chunk&1)*128+(l>>3)*16+(l&1)*8  [(l&7)*16 == ((l>>1)&3)*32+(l&1)*16].
__device__ __forceinline__ void stage_q256(
    const unsigned short* __restrict__ src,   // qbf + (b*C + kt*64)*N + n0
    char* dst, int t) {
  const int l = t & 63, wid = t >> 6;
  const int dd = (l >> 1) & 3;
  const int nb = (l >> 3) * 16 + (l & 1) * 8;
#pragma unroll
  for (int i = 0; i < 4; ++i) {
    const int chunk = wid * 4 + i;
    gload_lds16(src + (size_t)((chunk >> 1) * 4 + dd) * N_ + (chunk & 1) * 128 + nb,
                dst + chunk * 1024);
  }
}

// One phase: quadrant (NA = n-frag half, CB = c-frag half).
// LOADA: issue 8 tr_read pairs for af half; LOADB: 4 b128 for bf half.
// af persists across phases (combined after lgkmcnt per rule 18).
template <int NA, int CB, bool LOADA, bool LOADB, bool WAITV>
__device__ __forceinline__ void phase256(
    const char* Qc, const char* Pc, int l, int wn2, int wc,
    short4t (&aflo)[4][2], short4t (&afhi)[4][2], short8 (&af)[4][2],
    short8 (&bf)[2][2], f32x4 (&acc)[8][4]) {
  const int g = l >> 4;
  if (LOADA) {
    const unsigned base = lds_off(Qc) + (unsigned)((wn2 * 8 + NA * 4) * 128 +
                                                   g * 4096 + (l & 15) * 2);
#pragma unroll
    for (int mf = 0; mf < 4; ++mf)
#pragma unroll
      for (int ks = 0; ks < 2; ++ks) {
        const unsigned a = base + mf * 128 + ks * 16384;
        asm volatile("ds_read_b64_tr_b16 %0, %2\n\t"
                     "ds_read_b64_tr_b16 %1, %2 offset:2048"
                     : "=&v"(aflo[mf][ks]), "=&v"(afhi[mf][ks]) : "v"(a));
      }
  }
  if (LOADB) {
#pragma unroll
    for (int cf = 0; cf < 2; ++cf)
#pragma unroll
      for (int ks = 0; ks < 2; ++ks) {
        const int c_l = wc * 64 + CB * 32 + cf * 16 + (l & 15);
        bf[cf][ks] = *(const short8*)(Pc + c_l * 128 +
                                      (((ks * 4 + g) ^ (c_l & 7)) * 16));
      }
  }
  BARRAW();
  LGKM0();
  __builtin_amdgcn_sched_barrier(0);   // rule 18: fence tr_read results
  if (LOADA) {
#pragma unroll
    for (int mf = 0; mf < 4; ++mf)
#pragma unroll
      for (int ks = 0; ks < 2; ++ks)
        af[mf][ks] = __builtin_shufflevector(aflo[mf][ks], afhi[mf][ks],
                                             0, 1, 2, 3, 4, 5, 6, 7);
  }
  __builtin_amdgcn_s_setprio(1);
#pragma unroll
  for (int mf = 0; mf < 4; ++mf)
#pragma unroll
    for (int cf = 0; cf < 2; ++cf)
#pragma unroll
      for (int ks = 0; ks < 2; ++ks)
        acc[NA * 4 + mf][CB * 2 + cf] = __builtin_amdgcn_mfma_f32_16x16x32_bf16(
            af[mf][ks], bf[cf][ks], acc[NA * 4 + mf][CB * 2 + cf], 0, 0, 0);
  __builtin_amdgcn_s_setprio(0);
  if (WAITV) VMWAIT(0);
  BARRAW();
}

// ---------------------------------------------------------------- K1:
// x fp32 -> qbf bf16 + per-row sums. Pure stream.
__global__ __launch_bounds__(256) void k1_convert(
    const float* __restrict__ x, unsigned short* __restrict__ qbf,
    float* __restrict__ partial) {
  __shared__ float wsum[4];
  const size_t base = (size_t)blockIdx.x * N_;
  const int t = threadIdx.x;
  float s = 0.f;
#pragma unroll
  for (int k = 0; k < 4; ++k) {
    const int idx = (t + k * 256) * 4;
    float4 v = *(const float4*)(x + base + idx);
    *(ushort4*)(qbf + base + idx) = cvt4(v);
    s += (v.x + v.y) + (v.z + v.w);
  }
#pragma unroll
  for (int o = 1; o < 64; o <<= 1) s += __shfl_xor(s, o);
  if ((t & 63) == 0) wsum[t >> 6] = s;
  __syncthreads();
  if (t == 0) partial[blockIdx.x] = (wsum[0] + wsum[1]) + (wsum[2] + wsum[3]);
}

// ---------------------------------------------------------------- K2: SE MLP
__global__ __launch_bounds__(256) void k2_se(
    const float* __restrict__ partial, const float* __restrict__ gamma,
    const float* __restrict__ W1, const float* __restrict__ b1,
    const float* __restrict__ W2, const float* __restrict__ b2,
    float* __restrict__ gse) {
  __shared__ float se_s[C_];
  __shared__ float hp[4][CH_];
  __shared__ float h_s[CH_];
  const int b = blockIdx.x, t = threadIdx.x;
  for (int c = t; c < C_; c += 256)
    se_s[c] = partial[b * C_ + c] * (1.0f / (float)N_);
  __syncthreads();
  {
    const int h = t & 63, seg = t >> 6;
    float a = 0.f;
    const int cb = seg * 128;
    for (int c = cb; c < cb + 128; ++c) a += se_s[c] * W1[c * CH_ + h];
    hp[seg][h] = a;
  }
  __syncthreads();
  if (t < CH_) {
    float a = b1[t] + hp[0][t] + hp[1][t] + hp[2][t] + hp[3][t];
    h_s[t] = fmaxf(a, 0.f);
  }
  __syncthreads();
  const float g = gamma[0];
  for (int c = t; c < C_; c += 256) {
    float a = b2[c];
#pragma unroll
    for (int hh = 0; hh < CH_; ++hh) a += h_s[hh] * W2[hh * C_ + c];
    const float sig = 1.0f / (1.0f + __expf(-a));
    gse[b * C_ + c] = g * sig;
  }
}

// ---------------------------------------------------------------- K3 (R9):
__global__ __launch_bounds__(512) void k3_energy(
    const unsigned short* __restrict__ qbf, float* __restrict__ ep) {
  __shared__ alignas(16) char lds[65536];
  const int orig = blockIdx.x;
  const int wg = (orig & 7) * 80 + (orig >> 3);   // 640 = 8 x 80 bijective
  const int b = wg / 40;
  const int rem = wg % 40;
  const int kc = rem / 10;
  const int tid = rem % 10;
  int i, j;
  if (tid < 4)      { i = 0; j = tid; }
  else if (tid < 7) { i = 1; j = tid - 3; }
  else if (tid < 9) { i = 2; j = tid - 5; }
  else              { i = 3; j = 3; }
  const int c0 = i * 128, d0 = j * 128;
  const bool diag = (i == j);
  const unsigned short* qb = qbf + (size_t)b * C_ * N_ + kc * 1024;
  const int t = threadIdx.x, l = t & 63, wid = t >> 6;
  const int wd = wid >> 1, wcc = wid & 1;
  f32x4 acc[2][4];
#pragma unroll
  for (int m = 0; m < 2; ++m)
#pragma unroll
    for (int n = 0; n < 4; ++n) acc[m][n] = (f32x4){0.f, 0.f, 0.f, 0.f};
  char* A0 = lds;             char* B0 = lds + 16384;
  char* A1 = lds + 32768;     char* B1 = lds + 49152;
  const unsigned short* cp = qb + (size_t)c0 * N_;
  const unsigned short* dp = qb + (size_t)d0 * N_;

  stage_pair<2>(cp, dp, A0, B0, t, 0, !diag);
  for (int kt = 0; kt < 16; ++kt) {
    char* curA = (kt & 1) ? A1 : A0;
    char* curB = (kt & 1) ? B1 : B0;
    char* nxtA = (kt & 1) ? A0 : A1;
    char* nxtB = (kt & 1) ? B0 : B1;
    if (kt < 15) {
      stage_pair<2>(cp, dp, nxtA, nxtB, t, (kt + 1) * 64, !diag);
      if (diag) { VMWAIT(2); } else { VMWAIT(4); }
    } else {
      VMWAIT(0);
    }
    BARRAW();
    gemm_step_t<2, 4>(diag ? curA : curB, curA, l, wd, wcc, acc);
    BARRAW();
  }

  float* Lf = (float*)lds;
  float* eb = ep + ((size_t)(kc * B_ + b)) * C_ * C_;
#pragma unroll
  for (int df = 0; df < 2; ++df)
#pragma unroll
    for (int cf = 0; cf < 4; ++cf) {
      const int c_l = wcc * 64 + cf * 16 + (l & 15);
      const int d4 = wd * 32 + df * 16 + ((l >> 4) << 2);
      *(float4*)&Lf[c_l * 128 + (d4 ^ ((c_l & 7) << 2))] =
          *(const float4*)&acc[df][cf];
    }
  __syncthreads();
#pragma unroll
  for (int jj = 0; jj < 8; ++jj) {
    const int row = jj * 16 + (t >> 5);
    const int col4 = (t & 31) * 4;
    float4 v = *(const float4*)&Lf[row * 128 + (col4 ^ ((row & 7) << 2))];
    *(float4*)&eb[(size_t)(c0 + row) * C_ + d0 + col4] = v;
  }
  if (!diag) {
    __syncthreads();
#pragma unroll
    for (int df = 0; df < 2; ++df)
#pragma unroll
      for (int cf = 0; cf < 4; ++cf) {
        const int c_l = wcc * 64 + cf * 16 + (l & 15);
#pragma unroll
        for (int r = 0; r < 4; ++r) {
          const int d_l = wd * 32 + df * 16 + ((l >> 4) << 2) + r;
          Lf[d_l * 128 + (c_l ^ ((d_l & 7) << 2))] = acc[df][cf][r];
        }
      }
    __syncthreads();
#pragma unroll
    for (int jj = 0; jj < 8; ++jj) {
      const int row = jj * 16 + (t >> 5);
      const int col4 = (t & 31) * 4;
      float4 v = *(const float4*)&Lf[row * 128 + (col4 ^ ((row & 7) << 2))];
      *(float4*)&eb[(size_t)(d0 + row) * C_ + c0 + col4] = v;
    }
  }
}

// ---------------------------------------------------------------- K4 (R9):
__global__ __launch_bounds__(256) void k4_softmax(const float* __restrict__ ep,
                                                  unsigned short* __restrict__ att) {
  const int t = threadIdx.x, l = t & 63, wid = t >> 6;
  const size_t row = (size_t)blockIdx.x * 4 + wid;
  f32x4 v0 = (f32x4){0.f, 0.f, 0.f, 0.f}, v1 = v0;
#pragma unroll
  for (int k = 0; k < 4; ++k) {
    const f32x4* er = (const f32x4*)(ep + ((size_t)k * B_ * C_ + row) * C_);
    v0 += er[l];
    v1 += er[64 + l];
  }
  float mn = fminf(fminf(fminf(v0[0], v0[1]), fminf(v0[2], v0[3])),
                   fminf(fminf(v1[0], v1[1]), fminf(v1[2], v1[3])));
#pragma unroll
  for (int s = 1; s < 64; s <<= 1) mn = fminf(mn, __shfl_xor(mn, s));
  float e0 = __expf(mn - v0[0]), e1 = __expf(mn - v0[1]);
  float e2 = __expf(mn - v0[2]), e3 = __expf(mn - v0[3]);
  float e4 = __expf(mn - v1[0]), e5 = __expf(mn - v1[1]);
  float e6 = __expf(mn - v1[2]), e7 = __expf(mn - v1[3]);
  float sm = ((e0 + e1) + (e2 + e3)) + ((e4 + e5) + (e6 + e7));
#pragma unroll
  for (int s = 1; s < 64; s <<= 1) sm += __shfl_xor(sm, s);
  const float inv = 1.0f / sm;
  unsigned short* ar = att + row * C_;
  ushort4 u0, u1;
  u0.x = f2bf(e0 * inv); u0.y = f2bf(e1 * inv);
  u0.z = f2bf(e2 * inv); u0.w = f2bf(e3 * inv);
  u1.x = f2bf(e4 * inv); u1.y = f2bf(e5 * inv);
  u1.z = f2bf(e6 * inv); u1.w = f2bf(e7 * inv);
  *(ushort4*)(ar + 4 * l) = u0;
  *(ushort4*)(ar + 256 + 4 * l) = u1;
}

// ---------------------------------------------------------------- K5:
// D[c][n] = att[c][:].q[:][n]. 256c x 256n tile, 8 waves (wn2 n-half x
// wc c-quarter), K=512 (8 x BK=64), 8-phase counted schedule. q via
// tr_read subtiles; att via swizzled b128. Epilogue: 2 LDS sweeps,
// out = gse[c]*D + bf16(x) (XBF), 512B-contiguous stores.
__global__ __launch_bounds__(512) void k5_pv(
    const unsigned short* __restrict__ att, const unsigned short* __restrict__ qbf,
    const float* __restrict__ gse, float* __restrict__ out) {
  __shared__ alignas(16) char lds[131072];
  const int orig = blockIdx.x;
  const int wg = (orig & 7) * 64 + (orig >> 3);   // 512 = 8 x 64 bijective
  const int b = wg >> 5;                           // 2 batches per XCD
  const int rem = wg & 31;
  const int c0 = (rem & 1) * 256, n0 = (rem >> 1) * 256;
  const int t = threadIdx.x, l = t & 63, wid = t >> 6;
  const int wn2 = wid >> 2, wc = wid & 3;
  const unsigned short* ab = att + (size_t)b * C_ * C_ + (size_t)c0 * C_;
  const unsigned short* qb = qbf + (size_t)b * C_ * N_ + n0;   // + d*N_
  f32x4 acc[8][4];
#pragma unroll
  for (int m = 0; m < 8; ++m)
#pragma unroll
    for (int n = 0; n < 4; ++n) acc[m][n] = (f32x4){0.f, 0.f, 0.f, 0.f};
  char* P0 = lds;            char* P1 = lds + 32768;    // att bufs
  char* Q0 = lds + 65536;    char* Q1 = lds + 98304;    // q bufs

  short4t aflo[4][2], afhi[4][2];
  short8 af[4][2], bf[2][2];

  stage_att256(ab, P0, t, 0);
  stage_q256(qb, Q0, t);
  VMWAIT(0);
  BARRAW();
  for (int kt = 0; kt < 8; ++kt) {
    const char* Pc = (kt & 1) ? P1 : P0;
    const char* Qc = (kt & 1) ? Q1 : Q0;
    char* Pn = (kt & 1) ? P0 : P1;
    char* Qn = (kt & 1) ? Q0 : Q1;
    if (kt < 7) {   // issue ALL next-tile loads at phase 0 (3.5-phase cover)
      stage_att256(ab, Pn, t, (kt + 1) * 64);
      stage_q256(qb + (size_t)(kt + 1) * 64 * N_, Qn, t);
      phase256<0, 0, true,  true,  false>(Qc, Pc, l, wn2, wc, aflo, afhi, af, bf, acc);
      phase256<0, 1, false, true,  false>(Qc, Pc, l, wn2, wc, aflo, afhi, af, bf, acc);
      phase256<1, 1, true,  false, false>(Qc, Pc, l, wn2, wc, aflo, afhi, af, bf, acc);
      phase256<1, 0, false, true,  true >(Qc, Pc, l, wn2, wc, aflo, afhi, af, bf, acc);
    } else {
      phase256<0, 0, true,  true,  false>(Qc, Pc, l, wn2, wc, aflo, afhi, af, bf, acc);
      phase256<0, 1, false, true,  false>(Qc, Pc, l, wn2, wc, aflo, afhi, af, bf, acc);
      phase256<1, 1, true,  false, false>(Qc, Pc, l, wn2, wc, aflo, afhi, af, bf, acc);
      phase256<1, 0, false, true,  false>(Qc, Pc, l, wn2, wc, aflo, afhi, af, bf, acc);
    }
  }

  // Epilogue: two n-half sweeps through 128KB LDS; fused out = g*D + x.
  float* Lf = (float*)lds;
  const unsigned short* xb = qbf + (size_t)b * C_ * N_;
  float* ob = out + (size_t)b * C_ * N_;
  const float* gseb = gse + b * C_;
  const int g16 = l >> 4;
#pragma unroll
  for (int s = 0; s < 2; ++s) {
    BARRAW();
    if (wn2 == s) {
#pragma unroll
      for (int m = 0; m < 8; ++m)
#pragma unroll
        for (int cf = 0; cf < 4; ++cf) {
          const int c_l = wc * 64 + cf * 16 + (l & 15);
          const int n4 = (m >> 2) * 64 + (m & 3) * 16 + g16 * 4;
          *(float4*)&Lf[c_l * 128 + (n4 ^ ((c_l & 7) << 2))] =
              *(const float4*)&acc[m][cf];
        }
    }
    BARRAW();
#pragma unroll
    for (int it = 0; it < 16; ++it) {
      const int row = it * 16 + (t >> 5);
      const int col4 = (t & 31) * 4;
      const int c = c0 + row;
      const float g = gseb[c];
      float4 v = *(const float4*)&Lf[row * 128 + (col4 ^ ((row & 7) << 2))];
      const size_t gofs = (size_t)c * N_ + n0 + s * 128 + col4;
      ushort4 xu = *(const ushort4*)(xb + gofs);
      float4 ov;
      ov.x = g * v.x + bf2f(xu.x);
      ov.y = g * v.y + bf2f(xu.y);
      ov.z = g * v.z + bf2f(xu.z);
      ov.w = g * v.w + bf2f(xu.w);
      *(float4*)(ob + gofs) = ov;
    }
  }
}

// ---------------------------------------------------------------- launch
extern "C" void kernel_launch(void* const* d_in, const int* in_sizes, int n_in,
                              void* d_out, int out_size, void* d_ws, size_t ws_size,
                              hipStream_t stream) {
  (void)in_sizes; (void)n_in; (void)out_size; (void)ws_size;
  const float* x     = (const float*)d_in[0];
  const float* gamma = (const float*)d_in[1];
  const float* W1    = (const float*)d_in[2];
  const float* b1    = (const float*)d_in[3];
  const float* W2    = (const float*)d_in[4];
  const float* b2    = (const float*)d_in[5];
  float* out = (float*)d_out;
  char* ws = (char*)d_ws;

  // ws: qbf bf16 64Mi | att bf16 8Mi | partial 32K | gse 32K  (~72.07 MiB)
  unsigned short* qbf     = (unsigned short*)(ws);
  unsigned short* att     = (unsigned short*)(ws + 67108864);
  float*          partial = (float*)(ws + 75497472);
  float*          gse     = (float*)(ws + 75530240);
  float* epartial = out;   // d_out[0:64Mi], k3 -> k4, dead before k5 writes out

  k1_convert<<<dim3(B_ * C_), dim3(256), 0, stream>>>(x, qbf, partial);
  k2_se<<<dim3(B_), dim3(256), 0, stream>>>(partial, gamma, W1, b1, W2, b2, gse);
  k3_energy<<<dim3(640), dim3(512), 0, stream>>>(qbf, epartial);
  k4_softmax<<<dim3(B_ * C_ / 4), dim3(256), 0, stream>>>(epartial, att);
  k5_pv<<<dim3(512), dim3(512), 0, stream>>>(att, qbf, gse, out);
}

// Round 12
// 189.793 us; speedup vs baseline: 1.6693x; 1.6693x over previous
//
// CAM+SE module, MI355X gfx950.
// R12: k5 8-phase CORRECTED per m201 template: counted waits only (vmcnt
// 2/4, never 0 in-loop), loads spread one half-tile per phase, phases
// consume linear LDS halves (c_l = CB*128+wc*32+cf*16 wave remap), 2
// barriers/K-tile, af reused per ks-half. k1/k2/k3/k4 = R9.
#include <hip/hip_runtime.h>
#include <cstdint>
#include <cstddef>

#define B_ 16
#define C_ 512
#define N_ 4096   // H*W
#define CH_ 64    // C/8

#define VMWAIT(n) asm volatile("s_waitcnt vmcnt(" #n ")" ::: "memory")
#define LGKM0()   asm volatile("s_waitcnt lgkmcnt(0)" ::: "memory")
#define BARRAW()  asm volatile("s_barrier" ::: "memory")
#define SCHEDBAR() __builtin_amdgcn_sched_barrier(0)

typedef __attribute__((ext_vector_type(8))) short short8;
typedef __attribute__((ext_vector_type(4))) short short4t;
typedef __attribute__((ext_vector_type(4))) float f32x4;

__device__ __forceinline__ unsigned short f2bf(float f) {
  union { float f; unsigned u; } v; v.f = f;
  unsigned r = v.u + 0x7FFFu + ((v.u >> 16) & 1u);   // RNE
  return (unsigned short)(r >> 16);
}
__device__ __forceinline__ float bf2f(unsigned short u) {
  union { unsigned u; float f; } v; v.u = ((unsigned)u) << 16;
  return v.f;
}
__device__ __forceinline__ ushort4 cvt4(float4 v) {
  ushort4 u; u.x = f2bf(v.x); u.y = f2bf(v.y); u.z = f2bf(v.z); u.w = f2bf(v.w);
  return u;
}
__device__ __forceinline__ void gload_lds16(const void* g, void* l) {
  __builtin_amdgcn_global_load_lds((__attribute__((address_space(1))) void*)g,
                                   (__attribute__((address_space(3))) void*)l,
                                   16, 0, 0);
}
__device__ __forceinline__ unsigned lds_off(const void* p) {
  return (unsigned)(size_t)(__attribute__((address_space(3))) const char*)p;
}

// ================= k3 helpers (unchanged from R9) =================
template <int CPW>
__device__ __forceinline__ void stage_pair(
    const unsigned short* __restrict__ Asrc, const unsigned short* __restrict__ Bsrc,
    char* Adst, char* Bdst, int t, int ko, bool doB) {
  const int l = t & 63, wid = t >> 6;
  const int srow = l >> 3, scc = l & 7;
#pragma unroll
  for (int i = 0; i < CPW; ++i) {
    const int chunk = wid * CPW + i;
    const int row = chunk * 8 + srow;
    const int cc = scc ^ (row & 7);
    gload_lds16(Asrc + (size_t)row * N_ + ko + cc * 8, Adst + chunk * 1024);
    if (doB)
      gload_lds16(Bsrc + (size_t)row * N_ + ko + cc * 8, Bdst + chunk * 1024);
  }
}
template <int MF, int NF>
__device__ __forceinline__ void gemm_step_t(const char* Abase, const char* Bbase,
                                            int l, int wA, int wB,
                                            f32x4 (&acc)[MF][NF]) {
#pragma unroll
  for (int ks = 0; ks < 2; ++ks) {
    short8 af[MF], bfv[NF];
#pragma unroll
    for (int m = 0; m < MF; ++m) {
      const int row = wA * (MF * 16) + m * 16 + (l & 15);
      const int ch = (ks * 4 + (l >> 4)) ^ (row & 7);
      af[m] = *(const short8*)(Abase + row * 128 + ch * 16);
    }
#pragma unroll
    for (int n = 0; n < NF; ++n) {
      const int row = wB * (NF * 16) + n * 16 + (l & 15);
      const int ch = (ks * 4 + (l >> 4)) ^ (row & 7);
      bfv[n] = *(const short8*)(Bbase + row * 128 + ch * 16);
    }
#pragma unroll
    for (int m = 0; m < MF; ++m)
#pragma unroll
      for (int n = 0; n < NF; ++n)
        acc[m][n] = __builtin_amdgcn_mfma_f32_16x16x32_bf16(af[m], bfv[n],
                                                            acc[m][n], 0, 0, 0);
  }
}

// ================= k5 half-tile staging (256^2 tile) =================
// att c-half h: rows 128h..128h+127 -> LDS chunks 16h..16h+15 (linear),
// XOR-swizzled source (rule 21). 2 loads/thread.
__device__ __forceinline__ void stage_att_half(
    const unsigned short* __restrict__ src, char* dst, int t, int ko, int h) {
  const int l = t & 63, wid = t >> 6;
  const int srow = l >> 3, scc = l & 7;
#pragma unroll
  for (int i = 0; i < 2; ++i) {
    const int chunk = h * 16 + wid * 2 + i;
    const int row = chunk * 8 + srow;
    const int cc = scc ^ (row & 7);
    gload_lds16(src + (size_t)row * C_ + ko + cc * 8, dst + chunk * 1024);
  }
}
// q d-half h: rows d 32h..32h+31 of the 64x256 d-major panel into the
// tr-subtiled layout (d>>2)*2048 + (n>>4)*128 + (d&3)*32 + (n&15)*2 ->
// LDS chunks 16h..16h+15 (linear). 2 loads/thread.
__device__ __forceinline__ void stage_q_half(
    const unsigned short* __restrict__ src,   // qbf + (b*C + kt*64)*N + n0
    char* dst, int t, int h) {
  const int l = t & 63, wid = t >> 6;
  const int dd = (l >> 1) & 3;
  const int nb = (l >> 3) * 16 + (l & 1) * 8;
#pragma unroll
  for (int i = 0; i < 2; ++i) {
    const int chunk = h * 16 + wid * 2 + i;
    gload_lds16(src + (size_t)((chunk >> 1) * 4 + dd) * N_ + (chunk & 1) * 128 + nb,
                dst + chunk * 1024);
  }
}

// af tr-reads for ks-half: 8 n-frags for this wave's n-half (16 tr_reads).
template <int KS>
__device__ __forceinline__ void load_af(const char* Qc, int l, int wn2,
                                        short4t (&lo)[8], short4t (&hi)[8]) {
  const unsigned base = lds_off(Qc) + KS * 16384 + (unsigned)((l >> 4) * 4096 +
                        wn2 * 1024 + (l & 15) * 2);
#pragma unroll
  for (int nf = 0; nf < 8; ++nf) {
    const unsigned a = base + nf * 128;
    asm volatile("ds_read_b64_tr_b16 %0, %2\n\t"
                 "ds_read_b64_tr_b16 %1, %2 offset:2048"
                 : "=&v"(lo[nf]), "=&v"(hi[nf]) : "v"(a));
  }
}
// bf b128 reads for (ks, c-half CB): 2 c-frags of this wave's c-quarter.
template <int KS, int CB>
__device__ __forceinline__ void load_bf(const char* Pc, int l, int wc,
                                        short8 (&bf)[2]) {
#pragma unroll
  for (int cf = 0; cf < 2; ++cf) {
    const int c_l = CB * 128 + wc * 32 + cf * 16 + (l & 15);
    bf[cf] = *(const short8*)(Pc + c_l * 128 +
                              (((KS * 4 + (l >> 4)) ^ (c_l & 7)) * 16));
  }
}
template <int CB>
__device__ __forceinline__ void mfma16(const short8 (&af)[8], const short8 (&bf)[2],
                                       f32x4 (&acc)[8][4]) {
  __builtin_amdgcn_s_setprio(1);
#pragma unroll
  for (int nf = 0; nf < 8; ++nf)
#pragma unroll
    for (int cf = 0; cf < 2; ++cf)
      acc[nf][CB * 2 + cf] = __builtin_amdgcn_mfma_f32_16x16x32_bf16(
          af[nf], bf[cf], acc[nf][CB * 2 + cf], 0, 0, 0);
  __builtin_amdgcn_s_setprio(0);
}

// ---------------------------------------------------------------- K1:
__global__ __launch_bounds__(256) void k1_convert(
    const float* __restrict__ x, unsigned short* __restrict__ qbf,
    float* __restrict__ partial) {
  __shared__ float wsum[4];
  const size_t base = (size_t)blockIdx.x * N_;
  const int t = threadIdx.x;
  float s = 0.f;
#pragma unroll
  for (int k = 0; k < 4; ++k) {
    const int idx = (t + k * 256) * 4;
    float4 v = *(const float4*)(x + base + idx);
    *(ushort4*)(qbf + base + idx) = cvt4(v);
    s += (v.x + v.y) + (v.z + v.w);
  }
#pragma unroll
  for (int o = 1; o < 64; o <<= 1) s += __shfl_xor(s, o);
  if ((t & 63) == 0) wsum[t >> 6] = s;
  __syncthreads();
  if (t == 0) partial[blockIdx.x] = (wsum[0] + wsum[1]) + (wsum[2] + wsum[3]);
}

// ---------------------------------------------------------------- K2: SE MLP
__global__ __launch_bounds__(256) void k2_se(
    const float* __restrict__ partial, const float* __restrict__ gamma,
    const float* __restrict__ W1, const float* __restrict__ b1,
    const float* __restrict__ W2, const float* __restrict__ b2,
    float* __restrict__ gse) {
  __shared__ float se_s[C_];
  __shared__ float hp[4][CH_];
  __shared__ float h_s[CH_];
  const int b = blockIdx.x, t = threadIdx.x;
  for (int c = t; c < C_; c += 256)
    se_s[c] = partial[b * C_ + c] * (1.0f / (float)N_);
  __syncthreads();
  {
    const int h = t & 63, seg = t >> 6;
    float a = 0.f;
    const int cb = seg * 128;
    for (int c = cb; c < cb + 128; ++c) a += se_s[c] * W1[c * CH_ + h];
    hp[seg][h] = a;
  }
  __syncthreads();
  if (t < CH_) {
    float a = b1[t] + hp[0][t] + hp[1][t] + hp[2][t] + hp[3][t];
    h_s[t] = fmaxf(a, 0.f);
  }
  __syncthreads();
  const float g = gamma[0];
  for (int c = t; c < C_; c += 256) {
    float a = b2[c];
#pragma unroll
    for (int hh = 0; hh < CH_; ++hh) a += h_s[hh] * W2[hh * C_ + c];
    const float sig = 1.0f / (1.0f + __expf(-a));
    gse[b * C_ + c] = g * sig;
  }
}

// ---------------------------------------------------------------- K3 (R9):
__global__ __launch_bounds__(512) void k3_energy(
    const unsigned short* __restrict__ qbf, float* __restrict__ ep) {
  __shared__ alignas(16) char lds[65536];
  const int orig = blockIdx.x;
  const int wg = (orig & 7) * 80 + (orig >> 3);   // 640 = 8 x 80 bijective
  const int b = wg / 40;
  const int rem = wg % 40;
  const int kc = rem / 10;
  const int tid = rem % 10;
  int i, j;
  if (tid < 4)      { i = 0; j = tid; }
  else if (tid < 7) { i = 1; j = tid - 3; }
  else if (tid < 9) { i = 2; j = tid - 5; }
  else              { i = 3; j = 3; }
  const int c0 = i * 128, d0 = j * 128;
  const bool diag = (i == j);
  const unsigned short* qb = qbf + (size_t)b * C_ * N_ + kc * 1024;
  const int t = threadIdx.x, l = t & 63, wid = t >> 6;
  const int wd = wid >> 1, wcc = wid & 1;
  f32x4 acc[2][4];
#pragma unroll
  for (int m = 0; m < 2; ++m)
#pragma unroll
    for (int n = 0; n < 4; ++n) acc[m][n] = (f32x4){0.f, 0.f, 0.f, 0.f};
  char* A0 = lds;             char* B0 = lds + 16384;
  char* A1 = lds + 32768;     char* B1 = lds + 49152;
  const unsigned short* cp = qb + (size_t)c0 * N_;
  const unsigned short* dp = qb + (size_t)d0 * N_;

  stage_pair<2>(cp, dp, A0, B0, t, 0, !diag);
  for (int kt = 0; kt < 16; ++kt) {
    char* curA = (kt & 1) ? A1 : A0;
    char* curB = (kt & 1) ? B1 : B0;
    char* nxtA = (kt & 1) ? A0 : A1;
    char* nxtB = (kt & 1) ? B0 : B1;
    if (kt < 15) {
      stage_pair<2>(cp, dp, nxtA, nxtB, t, (kt + 1) * 64, !diag);
      if (diag) { VMWAIT(2); } else { VMWAIT(4); }
    } else {
      VMWAIT(0);
    }
    BARRAW();
    gemm_step_t<2, 4>(diag ? curA : curB, curA, l, wd, wcc, acc);
    BARRAW();
  }

  float* Lf = (float*)lds;
  float* eb = ep + ((size_t)(kc * B_ + b)) * C_ * C_;
#pragma unroll
  for (int df = 0; df < 2; ++df)
#pragma unroll
    for (int cf = 0; cf < 4; ++cf) {
      const int c_l = wcc * 64 + cf * 16 + (l & 15);
      const int d4 = wd * 32 + df * 16 + ((l >> 4) << 2);
      *(float4*)&Lf[c_l * 128 + (d4 ^ ((c_l & 7) << 2))] =
          *(const float4*)&acc[df][cf];
    }
  __syncthreads();
#pragma unroll
  for (int jj = 0; jj < 8; ++jj) {
    const int row = jj * 16 + (t >> 5);
    const int col4 = (t & 31) * 4;
    float4 v = *(const float4*)&Lf[row * 128 + (col4 ^ ((row & 7) << 2))];
    *(float4*)&eb[(size_t)(c0 + row) * C_ + d0 + col4] = v;
  }
  if (!diag) {
    __syncthreads();
#pragma unroll
    for (int df = 0; df < 2; ++df)
#pragma unroll
      for (int cf = 0; cf < 4; ++cf) {
        const int c_l = wcc * 64 + cf * 16 + (l & 15);
#pragma unroll
        for (int r = 0; r < 4; ++r) {
          const int d_l = wd * 32 + df * 16 + ((l >> 4) << 2) + r;
          Lf[d_l * 128 + (c_l ^ ((d_l & 7) << 2))] = acc[df][cf][r];
        }
      }
    __syncthreads();
#pragma unroll
    for (int jj = 0; jj < 8; ++jj) {
      const int row = jj * 16 + (t >> 5);
      const int col4 = (t & 31) * 4;
      float4 v = *(const float4*)&Lf[row * 128 + (col4 ^ ((row & 7) << 2))];
      *(float4*)&eb[(size_t)(d0 + row) * C_ + c0 + col4] = v;
    }
  }
}

// ---------------------------------------------------------------- K4 (R9):
__global__ __launch_bounds__(256) void k4_softmax(const float* __restrict__ ep,
                                                  unsigned short* __restrict__ att) {
  const int t = threadIdx.x, l = t & 63, wid = t >> 6;
  const size_t row = (size_t)blockIdx.x * 4 + wid;
  f32x4 v0 = (f32x4){0.f, 0.f, 0.f, 0.f}, v1 = v0;
#pragma unroll
  for (int k = 0; k < 4; ++k) {
    const f32x4* er = (const f32x4*)(ep + ((size_t)k * B_ * C_ + row) * C_);
    v0 += er[l];
    v1 += er[64 + l];
  }
  float mn = fminf(fminf(fminf(v0[0], v0[1]), fminf(v0[2], v0[3])),
                   fminf(fminf(v1[0], v1[1]), fminf(v1[2], v1[3])));
#pragma unroll
  for (int s = 1; s < 64; s <<= 1) mn = fminf(mn, __shfl_xor(mn, s));
  float e0 = __expf(mn - v0[0]), e1 = __expf(mn - v0[1]);
  float e2 = __expf(mn - v0[2]), e3 = __expf(mn - v0[3]);
  float e4 = __expf(mn - v1[0]), e5 = __expf(mn - v1[1]);
  float e6 = __expf(mn - v1[2]), e7 = __expf(mn - v1[3]);
  float sm = ((e0 + e1) + (e2 + e3)) + ((e4 + e5) + (e6 + e7));
#pragma unroll
  for (int s = 1; s < 64; s <<= 1) sm += __shfl_xor(sm, s);
  const float inv = 1.0f / sm;
  unsigned short* ar = att + row * C_;
  ushort4 u0, u1;
  u0.x = f2bf(e0 * inv); u0.y = f2bf(e1 * inv);
  u0.z = f2bf(e2 * inv); u0.w = f2bf(e3 * inv);
  u1.x = f2bf(e4 * inv); u1.y = f2bf(e5 * inv);
  u1.z = f2bf(e6 * inv); u1.w = f2bf(e7 * inv);
  *(ushort4*)(ar + 4 * l) = u0;
  *(ushort4*)(ar + 256 + 4 * l) = u1;
}

// ---------------------------------------------------------------- K5:
// 256c x 256n tile, 8 waves (wn2 = n-half, wc = c-quarter within c-half),
// K=512 as 8 x BK=64. Per tile 4 phases (ks,CB) in order (0,0)(0,1)(1,1)
// (1,0); each phase stages ONE half-tile for kt+1; VMWAIT(2) @ph1,
// VMWAIT(4) @ph3 (counted, never 0 in-loop); 2 barriers/tile.
__global__ __launch_bounds__(512) void k5_pv(
    const unsigned short* __restrict__ att, const unsigned short* __restrict__ qbf,
    const float* __restrict__ gse, float* __restrict__ out) {
  __shared__ alignas(16) char lds[131072];
  const int orig = blockIdx.x;
  const int wg = (orig & 7) * 64 + (orig >> 3);   // 512 = 8 x 64 bijective
  const int b = wg >> 5;                           // 2 batches per XCD
  const int rem = wg & 31;
  const int c0 = (rem & 1) * 256, n0 = (rem >> 1) * 256;
  const int t = threadIdx.x, l = t & 63, wid = t >> 6;
  const int wn2 = wid >> 2, wc = wid & 3;
  const unsigned short* ab = att + (size_t)b * C_ * C_ + (size_t)c0 * C_;
  const unsigned short* qb = qbf + (size_t)b * C_ * N_ + n0;   // + d*N_
  f32x4 acc[8][4];
#pragma unroll
  for (int m = 0; m < 8; ++m)
#pragma unroll
    for (int n = 0; n < 4; ++n) acc[m][n] = (f32x4){0.f, 0.f, 0.f, 0.f};
  char* P0 = lds;            char* P1 = lds + 32768;    // att dbuf
  char* Q0 = lds + 65536;    char* Q1 = lds + 98304;    // q dbuf

  short4t lo[8], hi[8];
  short8 af[8], bf[2];

  // prologue: tile0, issue order a0,a1,q0,q1 (matches in-loop issue order)
  stage_att_half(ab, P0, t, 0, 0);
  stage_att_half(ab, P0, t, 0, 1);
  stage_q_half(qb, Q0, t, 0);
  stage_q_half(qb, Q0, t, 1);

  for (int kt = 0; kt < 8; ++kt) {
    const char* Pc = (kt & 1) ? P1 : P0;
    const char* Qc = (kt & 1) ? Q1 : Q0;
    char* Pn = (kt & 1) ? P0 : P1;
    char* Qn = (kt & 1) ? Q0 : Q1;
    const int ko = (kt + 1) * 64;
    const unsigned short* qn = qb + (size_t)ko * N_;
    // ---- ph1 (ks0, CB0): needs q-d0 (2 newer loads may fly) ----
    VMWAIT(2);
    BARRAW();
    load_af<0>(Qc, l, wn2, lo, hi);
    load_bf<0, 0>(Pc, l, wc, bf);
    if (kt < 7) stage_att_half(ab, Pn, t, ko, 0);
    LGKM0(); SCHEDBAR();
#pragma unroll
    for (int nf = 0; nf < 8; ++nf)
      af[nf] = __builtin_shufflevector(lo[nf], hi[nf], 0, 1, 2, 3, 4, 5, 6, 7);
    mfma16<0>(af, bf, acc);
    // ---- ph2 (ks0, CB1) ----
    load_bf<0, 1>(Pc, l, wc, bf);
    if (kt < 7) stage_att_half(ab, Pn, t, ko, 1);
    LGKM0(); SCHEDBAR();
    mfma16<1>(af, bf, acc);
    // ---- ph3 (ks1, CB1): needs q-d1 (4 newer loads may fly) ----
    if (kt < 7) { VMWAIT(4); } else { VMWAIT(0); }
    BARRAW();
    load_af<1>(Qc, l, wn2, lo, hi);
    load_bf<1, 1>(Pc, l, wc, bf);
    if (kt < 7) stage_q_half(qn, Qn, t, 0);
    LGKM0(); SCHEDBAR();
#pragma unroll
    for (int nf = 0; nf < 8; ++nf)
      af[nf] = __builtin_shufflevector(lo[nf], hi[nf], 0, 1, 2, 3, 4, 5, 6, 7);
    mfma16<1>(af, bf, acc);
    // ---- ph4 (ks1, CB0) ----
    load_bf<1, 0>(Pc, l, wc, bf);
    if (kt < 7) stage_q_half(qn, Qn, t, 1);
    LGKM0(); SCHEDBAR();
    mfma16<0>(af, bf, acc);
  }

  // Epilogue: two n-half sweeps through 128KB LDS; out = gse*D + bf16(x).
  float* Lf = (float*)lds;
  const unsigned short* xb = qbf + (size_t)b * C_ * N_;
  float* ob = out + (size_t)b * C_ * N_;
  const float* gseb = gse + b * C_;
  const int g16 = l >> 4;
#pragma unroll
  for (int s = 0; s < 2; ++s) {
    BARRAW();
    if (wn2 == s) {
#pragma unroll
      for (int nf = 0; nf < 8; ++nf)
#pragma unroll
        for (int j = 0; j < 4; ++j) {
          const int c_l = (j >> 1) * 128 + wc * 32 + (j & 1) * 16 + (l & 15);
          const int n4 = nf * 16 + g16 * 4;
          *(float4*)&Lf[c_l * 128 + (n4 ^ ((c_l & 7) << 2))] =
              *(const float4*)&acc[nf][j];
        }
    }
    BARRAW();
#pragma unroll
    for (int it = 0; it < 16; ++it) {
      const int row = it * 16 + (t >> 5);
      const int col4 = (t & 31) * 4;
      const int c = c0 + row;
      const float g = gseb[c];
      float4 v = *(const float4*)&Lf[row * 128 + (col4 ^ ((row & 7) << 2))];
      const size_t gofs = (size_t)c * N_ + n0 + s * 128 + col4;
      ushort4 xu = *(const ushort4*)(xb + gofs);
      float4 ov;
      ov.x = g * v.x + bf2f(xu.x);
      ov.y = g * v.y + bf2f(xu.y);
      ov.z = g * v.z + bf2f(xu.z);
      ov.w = g * v.w + bf2f(xu.w);
      *(float4*)(ob + gofs) = ov;
    }
  }
}

// ---------------------------------------------------------------- launch
extern "C" void kernel_launch(void* const* d_in, const int* in_sizes, int n_in,
                              void* d_out, int out_size, void* d_ws, size_t ws_size,
                              hipStream_t stream) {
  (void)in_sizes; (void)n_in; (void)out_size; (void)ws_size;
  const float* x     = (const float*)d_in[0];
  const float* gamma = (const float*)d_in[1];
  const float* W1    = (const float*)d_in[2];
  const float* b1    = (const float*)d_in[3];
  const float* W2    = (const float*)d_in[4];
  const float* b2    = (const float*)d_in[5];
  float* out = (float*)d_out;
  char* ws = (char*)d_ws;

  // ws: qbf bf16 64Mi | att bf16 8Mi | partial 32K | gse 32K  (~72.07 MiB)
  unsigned short* qbf     = (unsigned short*)(ws);
  unsigned short* att     = (unsigned short*)(ws + 67108864);
  float*          partial = (float*)(ws + 75497472);
  float*          gse     = (float*)(ws + 75530240);
  float* epartial = out;   // d_out[0:64Mi], k3 -> k4, dead before k5 writes out

  k1_convert<<<dim3(B_ * C_), dim3(256), 0, stream>>>(x, qbf, partial);
  k2_se<<<dim3(B_), dim3(256), 0, stream>>>(partial, gamma, W1, b1, W2, b2, gse);
  k3_energy<<<dim3(640), dim3(512), 0, stream>>>(qbf, epartial);
  k4_softmax<<<dim3(B_ * C_ / 4), dim3(256), 0, stream>>>(epartial, att);
  k5_pv<<<dim3(512), dim3(512), 0, stream>>>(att, qbf, gse, out);
}